// Round 11
// baseline (218.034 us; speedup 1.0000x reference)
//
#include <hip/hip_runtime.h>
#include <math.h>

#define BATCH 256
#define NPTS  16384
#define TPB   256
#define MID_TPB 1024

// pass1 tiling: grid (BATCH, P1_CHUNKS); 4 waves/block; wave handles 512 pts
#define P1_CHUNKS     8
#define P1_PTS_BLOCK  (NPTS / P1_CHUNKS)      // 2048
#define P1_ITERS      8                        // 8 iters x 64 pts = 512 pts/wave

// ---- workspace: per-(batch,chunk) partials, stride 256 floats ----
// [0..63] chMax, [64..127] chSum, [128..191] chSumSq, [192..200] moments,
// [208..210] chunk proj-min, [211..213] chunk proj-max (written by ext_kernel)
#define PART_STRIDE 256

typedef __bf16 bf16x8  __attribute__((ext_vector_type(8)));
typedef float  floatx4 __attribute__((ext_vector_type(4)));
typedef float  floatx2 __attribute__((ext_vector_type(2)));

// ---------------- shared: all-thread 3x3 Jacobi eigh ----------------
// Uniform inputs -> uniform branches -> bitwise-identical results in every
// kernel that calls it (ext_kernel and final_kernel must agree exactly).
// Runtime column selects via ternaries (rule-#20: no runtime-indexed regs).
__device__ __forceinline__ void eigh3(const float mo9[9],
    float& cx, float& cy, float& cz,
    float& e0x, float& e0y, float& e0z,
    float& e1x, float& e1y, float& e1z,
    float& e2x, float& e2y, float& e2z,
    float& ena, float& enb, float& enc) {
    const float nin = 1.0f / (float)NPTS;
    cx = mo9[0] * nin; cy = mo9[1] * nin; cz = mo9[2] * nin;
    float A[3][3];
    A[0][0] = mo9[3] * nin - cx * cx; A[0][1] = mo9[4] * nin - cx * cy;
    A[0][2] = mo9[5] * nin - cx * cz;
    A[1][1] = mo9[6] * nin - cy * cy; A[1][2] = mo9[7] * nin - cy * cz;
    A[2][2] = mo9[8] * nin - cz * cz;
    A[1][0] = A[0][1]; A[2][0] = A[0][2]; A[2][1] = A[1][2];
    float V[3][3] = {{1, 0, 0}, {0, 1, 0}, {0, 0, 1}};
    const int PP[3] = {0, 0, 1};
    const int QQ[3] = {1, 2, 2};
    for (int sweep = 0; sweep < 7; ++sweep) {
#pragma unroll
        for (int r3 = 0; r3 < 3; ++r3) {
            int p = PP[r3], q = QQ[r3];
            float apq = A[p][q];
            if (fabsf(apq) < 1e-35f) continue;
            float theta = (A[q][q] - A[p][p]) / (2.0f * apq);
            float tt = 1.0f / (fabsf(theta) + sqrtf(fmaf(theta, theta, 1.0f)));
            if (theta < 0.0f) tt = -tt;
            float c = 1.0f / sqrtf(fmaf(tt, tt, 1.0f)), s = tt * c;
            float apq_t = tt * apq;
            A[p][p] -= apq_t;
            A[q][q] += apq_t;
            A[p][q] = A[q][p] = 0.0f;
#pragma unroll
            for (int r = 0; r < 3; ++r) {
                if (r != p && r != q) {
                    float arp = A[r][p], arq = A[r][q];
                    A[r][p] = A[p][r] = c * arp - s * arq;
                    A[r][q] = A[q][r] = s * arp + c * arq;
                }
                float vrp = V[r][p], vrq = V[r][q];
                V[r][p] = c * vrp - s * vrq;
                V[r][q] = s * vrp + c * vrq;
            }
        }
    }
    float w0 = A[0][0], w1v = A[1][1], w2v = A[2][2];
    int i0 = 0, i1 = 1, i2 = 2, sw;
    {
        float wa = w0, wb = w1v, wc = w2v, swf;
        if (wa < wb) { sw = i0; i0 = i1; i1 = sw; swf = wa; wa = wb; wb = swf; }
        if (wa < wc) { sw = i0; i0 = i2; i2 = sw; swf = wa; wa = wc; wc = swf; }
        if (wb < wc) { sw = i1; i1 = i2; i2 = sw; swf = wb; wb = wc; wc = swf; }
    }
#define SEL3(a0, a1, a2, id) ((id) == 0 ? (a0) : ((id) == 1 ? (a1) : (a2)))
    e0x = SEL3(V[0][0], V[0][1], V[0][2], i0);
    e0y = SEL3(V[1][0], V[1][1], V[1][2], i0);
    e0z = SEL3(V[2][0], V[2][1], V[2][2], i0);
    e1x = SEL3(V[0][0], V[0][1], V[0][2], i1);
    e1y = SEL3(V[1][0], V[1][1], V[1][2], i1);
    e1z = SEL3(V[2][0], V[2][1], V[2][2], i1);
    e2x = SEL3(V[0][0], V[0][1], V[0][2], i2);
    e2y = SEL3(V[1][0], V[1][1], V[1][2], i2);
    e2z = SEL3(V[2][0], V[2][1], V[2][2], i2);
    const float esum = w0 + w1v + w2v + 1e-8f;
    ena = SEL3(w0, w1v, w2v, i0) / esum;
    enb = SEL3(w0, w1v, w2v, i1) / esum;
    enc = SEL3(w0, w1v, w2v, i2) / esum;
#undef SEL3
}

// ---------------- pass 1: coord moments + MFMA point-MLP + channel stats ----------------
// A-frag (16x16x32 bf16): A[m = lane&15][k = (lane>>4)*8 + j]
// B-frag:                 B[k = (lane>>4)*8 + j][n = lane&15]
// C/D layout:             col = lane&15, row = (lane>>4)*4 + reg   [m89]
// R16: pass1 BYTE-IDENTICAL to R14/R15 (verified 60.5-61.3us). pass1 is at
// its practical floor: stats 2.5 instr/value, A-build 2 fma/hidden,
// occupancy reg-blocked ~16 waves/CU (R11/R12 spill evidence). This round
// splits mid along its dependency chain (R15 probe: mid changes -> -8us,
// so mid IS on the critical path).
// History: R6 biasC; R8 packed add/fma; R10 rolled prefetch + deferred-relu;
// R11/R12 occupancy attack CLOSED (arch/acc split spills); R14 LDS sem
// broadcast; R15 all-thread eigh + scan unroll (-8us total).
// NOTE: all arrays constant-indexed (R3). Spill tripwire: WRITE_SIZE >~2MB.
// NOTE2 (R5): no device-scope-fence fusion (63 -> 357us disaster).
__global__ __launch_bounds__(TPB, 4)
void pass1_kernel(const float* __restrict__ x, const float* __restrict__ W1,
                  const float* __restrict__ b1, const float* __restrict__ W2,
                  const float* __restrict__ b2, float* __restrict__ ws) {
    const int b     = blockIdx.x;
    const int chunk = blockIdx.y;
    const int tid   = threadIdx.x;
    const int lane  = tid & 63;
    const int wave  = tid >> 6;
    const int quad  = lane >> 4;
    const int l15   = lane & 15;

    __shared__ floatx2 sem_lds[4][64];   // [wave][pt] = 2KB, wave-private

    bf16x8  Bf[4];
    floatx4 biasC[4];
#pragma unroll
    for (int t = 0; t < 4; ++t) {
        int n = t * 16 + l15;
#pragma unroll
        for (int j = 0; j < 8; ++j)
            Bf[t][j] = (__bf16)W2[(quad * 8 + j) * 64 + n];
        float bb = b2[n];
        biasC[t] = (floatx4){bb, bb, bb, bb};
    }
    floatx2 w1a2[4], w1b2[4], b1r2[4];
#pragma unroll
    for (int jp = 0; jp < 4; ++jp) {
        int jj = quad * 8 + jp * 2;
        w1a2[jp] = (floatx2){W1[jj],      W1[jj + 1]};
        w1b2[jp] = (floatx2){W1[32 + jj], W1[32 + jj + 1]};
        b1r2[jp] = (floatx2){b1[jj],      b1[jj + 1]};
    }

    const floatx2 zero2 = {0.f, 0.f};
    float   vmaxr[4] = {0.f, 0.f, 0.f, 0.f};   // raw max, init 0 == deferred relu
    floatx2 vsum[4], vsq[4];
#pragma unroll
    for (int t = 0; t < 4; ++t) {
        vsum[t] = zero2;
        vsq[t]  = zero2;
    }
    float mo[9];
#pragma unroll
    for (int j = 0; j < 9; ++j) mo[j] = 0.f;

    const float* xb = x + ((size_t)b * NPTS + (size_t)chunk * P1_PTS_BLOCK) * 5;
    const float* pc = xb + (size_t)wave * (P1_ITERS * 64) * 5 + (size_t)lane * 5;

    float c0 = pc[0], c1 = pc[1], c2 = pc[2], s0 = pc[3], s1 = pc[4];

#pragma unroll 1
    for (int it = 0; it < P1_ITERS; ++it) {
        const float* pn = pc + ((it < P1_ITERS - 1) ? 320 : 0);
        float n0 = pn[0], n1 = pn[1], n2 = pn[2], n3 = pn[3], n4 = pn[4];

        sem_lds[wave][lane] = (floatx2){s0, s1};

        mo[0] += c0; mo[1] += c1; mo[2] += c2;
        mo[3] = fmaf(c0, c0, mo[3]); mo[4] = fmaf(c0, c1, mo[4]); mo[5] = fmaf(c0, c2, mo[5]);
        mo[6] = fmaf(c1, c1, mo[6]); mo[7] = fmaf(c1, c2, mo[7]); mo[8] = fmaf(c2, c2, mo[8]);

        floatx2 gsem[4];
#pragma unroll
        for (int g = 0; g < 4; ++g)
            gsem[g] = sem_lds[wave][g * 16 + l15];

#pragma unroll
        for (int g = 0; g < 4; ++g) {
            floatx2 G0 = {gsem[g][0], gsem[g][0]};
            floatx2 G1 = {gsem[g][1], gsem[g][1]};
            bf16x8 Af;
#pragma unroll
            for (int jp = 0; jp < 4; ++jp) {
                floatx2 h = __builtin_elementwise_fma(
                    G0, w1a2[jp], __builtin_elementwise_fma(G1, w1b2[jp], b1r2[jp]));
                h = __builtin_elementwise_max(h, zero2);
                Af[2 * jp]     = (__bf16)h[0];
                Af[2 * jp + 1] = (__bf16)h[1];
            }
#pragma unroll
            for (int t = 0; t < 4; ++t) {
                floatx4 D = __builtin_amdgcn_mfma_f32_16x16x32_bf16(Af, Bf[t], biasC[t], 0, 0, 0);
                vmaxr[t] = fmaxf(fmaxf(D[0], D[1]),
                                 fmaxf(fmaxf(D[2], D[3]), vmaxr[t]));
                floatx2 d01 = {D[0], D[1]}, d23 = {D[2], D[3]};
                floatx2 p01 = __builtin_elementwise_max(d01, zero2);
                floatx2 p23 = __builtin_elementwise_max(d23, zero2);
                vsum[t] += p01 + p23;
                vsq[t]   = __builtin_elementwise_fma(p01, p01,
                               __builtin_elementwise_fma(p23, p23, vsq[t]));
            }
        }

        c0 = n0; c1 = n1; c2 = n2; s0 = n3; s1 = n4;
        pc += 320;
    }

    float vmax[4], vs[4], vq[4];
#pragma unroll
    for (int t = 0; t < 4; ++t) {
        vmax[t] = vmaxr[t];
        vs[t]   = vsum[t][0] + vsum[t][1];
        vq[t]   = vsq[t][0] + vsq[t][1];
        vmax[t] = fmaxf(vmax[t], __shfl_xor(vmax[t], 16));
        vmax[t] = fmaxf(vmax[t], __shfl_xor(vmax[t], 32));
        vs[t] += __shfl_xor(vs[t], 16);
        vs[t] += __shfl_xor(vs[t], 32);
        vq[t] += __shfl_xor(vq[t], 16);
        vq[t] += __shfl_xor(vq[t], 32);
    }
#pragma unroll
    for (int j = 0; j < 9; ++j) {
        float v = mo[j];
#pragma unroll
        for (int o = 32; o > 0; o >>= 1) v += __shfl_xor(v, o);
        mo[j] = v;
    }

    __shared__ float red[4][201];
    if (quad == 0) {
#pragma unroll
        for (int t = 0; t < 4; ++t) {
            red[wave][t * 16 + l15]       = vmax[t];
            red[wave][64 + t * 16 + l15]  = vs[t];
            red[wave][128 + t * 16 + l15] = vq[t];
        }
    }
    if (lane == 0) {
#pragma unroll
        for (int j = 0; j < 9; ++j) red[wave][192 + j] = mo[j];
    }
    __syncthreads();

    if (tid < 201) {
        float v0 = red[0][tid], v1 = red[1][tid], v2 = red[2][tid], v3 = red[3][tid];
        float r = (tid < 64) ? fmaxf(fmaxf(v0, v1), fmaxf(v2, v3))
                             : (v0 + v1) + (v2 + v3);
        ws[(size_t)(b * P1_CHUNKS + chunk) * PART_STRIDE + tid] = r;
    }
}

// ---------------- ext: per-chunk projection extents (8 blocks/CU, BW-bound) ----------------
// Each block: redundant all-thread eigh from the 9 moment sums (bitwise
// identical across blocks/kernels), scan its 2048-pt chunk (8 pts/thread),
// write per-chunk min/max to ws slots 208..213.
__global__ __launch_bounds__(TPB)
void ext_kernel(const float* __restrict__ x, const float* __restrict__ ws_in,
                float* __restrict__ ws) {
    const int b = blockIdx.x, chunk = blockIdx.y, t = threadIdx.x;
    const int lane = t & 63, wv = t >> 6;

    // moment sums over the 8 chunk rows (uniform across threads)
    const float* wrow = ws_in + (size_t)b * P1_CHUNKS * PART_STRIDE;
    float m9[9];
#pragma unroll
    for (int j = 0; j < 9; ++j) {
        float a = 0.f;
#pragma unroll
        for (int i = 0; i < P1_CHUNKS; ++i) a += wrow[i * PART_STRIDE + 192 + j];
        m9[j] = a;
    }
    float cx, cy, cz, e0x, e0y, e0z, e1x, e1y, e1z, e2x, e2y, e2z, ena, enb, enc;
    eigh3(m9, cx, cy, cz, e0x, e0y, e0z, e1x, e1y, e1z, e2x, e2y, e2z, ena, enb, enc);

    const float* xb = x + ((size_t)b * NPTS + (size_t)chunk * P1_PTS_BLOCK) * 5;
    float mn0 = 3.4e38f, mn1 = 3.4e38f, mn2 = 3.4e38f;
    float mx0 = -3.4e38f, mx1 = -3.4e38f, mx2 = -3.4e38f;
#pragma unroll
    for (int i = 0; i < P1_PTS_BLOCK / TPB; ++i) {
        const float* p = xb + (size_t)(i * TPB + t) * 5;
        float c0 = p[0] - cx, c1 = p[1] - cy, c2 = p[2] - cz;
        float p0 = fmaf(c0, e0x, fmaf(c1, e0y, c2 * e0z));
        float p1 = fmaf(c0, e1x, fmaf(c1, e1y, c2 * e1z));
        float p2 = fmaf(c0, e2x, fmaf(c1, e2y, c2 * e2z));
        mn0 = fminf(mn0, p0); mx0 = fmaxf(mx0, p0);
        mn1 = fminf(mn1, p1); mx1 = fmaxf(mx1, p1);
        mn2 = fminf(mn2, p2); mx2 = fmaxf(mx2, p2);
    }
    __shared__ float red2[4][6];
#pragma unroll
    for (int o = 32; o > 0; o >>= 1) {
        mn0 = fminf(mn0, __shfl_xor(mn0, o)); mx0 = fmaxf(mx0, __shfl_xor(mx0, o));
        mn1 = fminf(mn1, __shfl_xor(mn1, o)); mx1 = fmaxf(mx1, __shfl_xor(mx1, o));
        mn2 = fminf(mn2, __shfl_xor(mn2, o)); mx2 = fmaxf(mx2, __shfl_xor(mx2, o));
    }
    if (lane == 0) {
        red2[wv][0] = mn0; red2[wv][1] = mn1; red2[wv][2] = mn2;
        red2[wv][3] = mx0; red2[wv][4] = mx1; red2[wv][5] = mx2;
    }
    __syncthreads();
    if (t < 6) {
        float a = red2[0][t];
#pragma unroll
        for (int w = 1; w < 4; ++w)
            a = (t < 3) ? fminf(a, red2[w][t]) : fmaxf(a, red2[w][t]);
        ws[(size_t)(b * P1_CHUNKS + chunk) * PART_STRIDE + 208 + t] = a;
    }
}

// ---------------- final: reduce partials + eigh + g + MLP (no x re-read) ----------------
__global__ __launch_bounds__(MID_TPB)
void final_kernel(const float* __restrict__ W3, const float* __restrict__ b3,
                  const float* __restrict__ W4, const float* __restrict__ b4,
                  const float* __restrict__ W5, const float* __restrict__ b5,
                  const float* __restrict__ ws, float* __restrict__ out) {
    const int b = blockIdx.x, t = threadIdx.x;

    __shared__ float comb[201];
    __shared__ float g[224];
    __shared__ float h1[256];
    __shared__ float h2[128];
    __shared__ float part[8][256];

    if (t < 201) {
        const float* base = ws + (size_t)b * P1_CHUNKS * PART_STRIDE + t;
        float acc = base[0];
        if (t < 64) {
#pragma unroll
            for (int i = 1; i < P1_CHUNKS; ++i) acc = fmaxf(acc, base[i * PART_STRIDE]);
        } else {
#pragma unroll
            for (int i = 1; i < P1_CHUNKS; ++i) acc += base[i * PART_STRIDE];
        }
        comb[t] = acc;
    }
    __syncthreads();

    // all-thread eigh (bitwise identical to ext_kernel's: same inputs/code)
    float m9[9];
#pragma unroll
    for (int j = 0; j < 9; ++j) m9[j] = comb[192 + j];
    float cx, cy, cz, e0x, e0y, e0z, e1x, e1y, e1z, e2x, e2y, e2z, ena, enb, enc;
    eigh3(m9, cx, cy, cz, e0x, e0y, e0z, e1x, e1y, e1z, e2x, e2y, e2z, ena, enb, enc);

    // --- assemble g(201) ---
    if (t < 64) {
        g[t] = comb[t];
        float s = comb[64 + t], sq = comb[128 + t];
        float avg = s * (1.0f / NPTS);
        g[64 + t] = avg;
        float var = (sq - s * avg) / (float)(NPTS - 1);
        g[128 + t] = sqrtf(fmaxf(var, 0.f));
    } else if (t < 73) {
        int j = t - 64;
        if (j < 3) {
            g[192 + j] = (j == 0) ? ena : ((j == 1) ? enb : enc);
        } else if (j < 6) {
            int d = j - 3;
            const float* wrow = ws + (size_t)b * P1_CHUNKS * PART_STRIDE;
            float mn = wrow[208 + d], mx = wrow[211 + d];
#pragma unroll
            for (int i = 1; i < P1_CHUNKS; ++i) {
                mn = fminf(mn, wrow[i * PART_STRIDE + 208 + d]);
                mx = fmaxf(mx, wrow[i * PART_STRIDE + 211 + d]);
            }
            g[195 + d] = mx - mn;
        } else {
            int d = j - 6;
            g[198 + d] = (d == 0) ? cx : ((d == 1) ? cy : cz);
        }
    }
    __syncthreads();

    // --- final MLP 201 -> 256 -> 128 -> 256, split-K over waves ---
    {
        int p = t >> 8, c = t & 255;
        int j0 = p * 51, j1 = min(201, j0 + 51);
        float a = 0.f;
        for (int j = j0; j < j1; ++j) a = fmaf(g[j], W3[j * 256 + c], a);
        part[p][c] = a;
    }
    __syncthreads();
    if (t < 256) {
        float a = b3[t] + (part[0][t] + part[1][t]) + (part[2][t] + part[3][t]);
        h1[t] = fmaxf(a, 0.f);
    }
    __syncthreads();
    {
        int p = t >> 7, c = t & 127;
        int j0 = p * 32;
        float a = 0.f;
#pragma unroll
        for (int j = j0; j < j0 + 32; ++j) a = fmaf(h1[j], W4[j * 128 + c], a);
        part[p][c] = a;
    }
    __syncthreads();
    if (t < 128) {
        float a = b4[t];
#pragma unroll
        for (int p = 0; p < 8; ++p) a += part[p][t];
        h2[t] = fmaxf(a, 0.f);
    }
    __syncthreads();
    {
        int p = t >> 8, c = t & 255;
        int j0 = p * 32;
        float a = 0.f;
#pragma unroll
        for (int j = j0; j < j0 + 32; ++j) a = fmaf(h2[j], W5[j * 256 + c], a);
        part[p][c] = a;
    }
    __syncthreads();
    if (t < 256) {
        float o = b5[t] + (part[0][t] + part[1][t]) + (part[2][t] + part[3][t]);
        out[(size_t)b * 256 + t] = o;
    }
}

extern "C" void kernel_launch(void* const* d_in, const int* in_sizes, int n_in,
                              void* d_out, int out_size, void* d_ws, size_t ws_size,
                              hipStream_t stream) {
    const float* x  = (const float*)d_in[0];
    const float* W1 = (const float*)d_in[1];
    const float* b1 = (const float*)d_in[2];
    const float* W2 = (const float*)d_in[3];
    const float* b2 = (const float*)d_in[4];
    const float* W3 = (const float*)d_in[5];
    const float* b3 = (const float*)d_in[6];
    const float* W4 = (const float*)d_in[7];
    const float* b4 = (const float*)d_in[8];
    const float* W5 = (const float*)d_in[9];
    const float* b5 = (const float*)d_in[10];
    float* out = (float*)d_out;
    float* ws  = (float*)d_ws;

    pass1_kernel<<<dim3(BATCH, P1_CHUNKS), TPB, 0, stream>>>(x, W1, b1, W2, b2, ws);
    ext_kernel<<<dim3(BATCH, P1_CHUNKS), TPB, 0, stream>>>(x, ws, ws);
    final_kernel<<<dim3(BATCH), MID_TPB, 0, stream>>>(W3, b3, W4, b4, W5, b5, ws, out);
}

// Round 12
// 204.016 us; speedup vs baseline: 1.0687x; 1.0687x over previous
//
#include <hip/hip_runtime.h>
#include <math.h>

#define BATCH 256
#define NPTS  16384
#define TPB   256
#define MID_TPB 1024

// pass1 tiling: grid (BATCH, P1_CHUNKS); 4 waves/block; wave handles 512 pts
#define P1_CHUNKS     8
#define P1_PTS_BLOCK  (NPTS / P1_CHUNKS)      // 2048
#define P1_ITERS      8                        // 8 iters x 64 pts = 512 pts/wave

// ---- workspace: per-(batch,chunk) partials, stride 256 floats ----
// [0..63] chMax, [64..127] chSum, [128..191] chSumSq, [192..200] moments
#define PART_STRIDE 256

typedef __bf16 bf16x8  __attribute__((ext_vector_type(8)));
typedef float  floatx4 __attribute__((ext_vector_type(4)));
typedef float  floatx2 __attribute__((ext_vector_type(2)));

// ---------------- pass 1: coord moments + MFMA point-MLP + channel stats ----------------
// A-frag (16x16x32 bf16): A[m = lane&15][k = (lane>>4)*8 + j]
// B-frag:                 B[k = (lane>>4)*8 + j][n = lane&15]
// C/D layout:             col = lane&15, row = (lane>>4)*4 + reg   [m89]
// R17 (post-mortem R16: 3-kernel split REGRESSED 204->218; extra dispatch +
// 2048 redundant eighs + second x pass cost more than the parallelism won.
// mid reverted to R15 form. This round: pass1's last identified stall —
// the intra-iter LDS RAW chain ds_write(sem)->ds_read(gsem)->A-build is
// back-to-back in the in-order DS pipe, ~150-240cy exposed with only the
// 9-op moments block hiding it; matches the ~27% all-wave-idle gap):
//  - NEW: double-buffered, 1-iter-ahead sem pipeline. Iter it writes
//    it+1's sem (n3,n4 from the existing prefetch) to buf[(it+1)&1] at END
//    of body, reads gnext[4] right after (in-order pipe, same-wave idiom
//    proven in R14), consumes at NEXT iter's A-build -> the DS round-trip
//    overlaps rotate+branch+prefetch+moments instead of stalling A-build.
//  - KEPT: rolled depth-1 prefetch (R10), deferred-relu raw max (R10),
//    biasC-as-C-operand (R6), packed add/fma stats (R8).
// History: R11/R12 occupancy attack CLOSED (unified-file arch/acc split
// spills: VGPR 32@w=8/40@w=6, WRITE 578/691MB); R6 direct sem loads
// regressed (latency); R9 full-unroll prefetch spilled (scratch).
// NOTE: all arrays constant-indexed (R3). Spill tripwire: WRITE_SIZE >~2MB.
// NOTE2 (R5): no device-scope-fence fusion (63 -> 357us disaster).
__global__ __launch_bounds__(TPB, 4)
void pass1_kernel(const float* __restrict__ x, const float* __restrict__ W1,
                  const float* __restrict__ b1, const float* __restrict__ W2,
                  const float* __restrict__ b2, float* __restrict__ ws) {
    const int b     = blockIdx.x;
    const int chunk = blockIdx.y;
    const int tid   = threadIdx.x;
    const int lane  = tid & 63;
    const int wave  = tid >> 6;
    const int quad  = lane >> 4;
    const int l15   = lane & 15;

    __shared__ floatx2 sem_lds[2][4][64];   // double-buffered, wave-private

    bf16x8  Bf[4];
    floatx4 biasC[4];
#pragma unroll
    for (int t = 0; t < 4; ++t) {
        int n = t * 16 + l15;
#pragma unroll
        for (int j = 0; j < 8; ++j)
            Bf[t][j] = (__bf16)W2[(quad * 8 + j) * 64 + n];
        float bb = b2[n];
        biasC[t] = (floatx4){bb, bb, bb, bb};
    }
    floatx2 w1a2[4], w1b2[4], b1r2[4];
#pragma unroll
    for (int jp = 0; jp < 4; ++jp) {
        int jj = quad * 8 + jp * 2;
        w1a2[jp] = (floatx2){W1[jj],      W1[jj + 1]};
        w1b2[jp] = (floatx2){W1[32 + jj], W1[32 + jj + 1]};
        b1r2[jp] = (floatx2){b1[jj],      b1[jj + 1]};
    }

    const floatx2 zero2 = {0.f, 0.f};
    float   vmaxr[4] = {0.f, 0.f, 0.f, 0.f};   // raw max, init 0 == deferred relu
    floatx2 vsum[4], vsq[4];
#pragma unroll
    for (int t = 0; t < 4; ++t) {
        vsum[t] = zero2;
        vsq[t]  = zero2;
    }
    float mo[9];
#pragma unroll
    for (int j = 0; j < 9; ++j) mo[j] = 0.f;

    const float* xb = x + ((size_t)b * NPTS + (size_t)chunk * P1_PTS_BLOCK) * 5;
    const float* pc = xb + (size_t)wave * (P1_ITERS * 64) * 5 + (size_t)lane * 5;

    // prologue: iter-0 point + seed buf0 with iter-0 sem, preload gcur
    float c0 = pc[0], c1 = pc[1], c2 = pc[2];
    {
        float s0 = pc[3], s1 = pc[4];
        sem_lds[0][wave][lane] = (floatx2){s0, s1};
    }
    floatx2 gcur[4];
#pragma unroll
    for (int g = 0; g < 4; ++g)
        gcur[g] = sem_lds[0][wave][g * 16 + l15];

#pragma unroll 1
    for (int it = 0; it < P1_ITERS; ++it) {
        // prefetch it+1 (wave-uniform clamp on last iter: harmless re-read)
        const float* pn = pc + ((it < P1_ITERS - 1) ? 320 : 0);
        float n0 = pn[0], n1 = pn[1], n2 = pn[2], n3 = pn[3], n4 = pn[4];

        mo[0] += c0; mo[1] += c1; mo[2] += c2;
        mo[3] = fmaf(c0, c0, mo[3]); mo[4] = fmaf(c0, c1, mo[4]); mo[5] = fmaf(c0, c2, mo[5]);
        mo[6] = fmaf(c1, c1, mo[6]); mo[7] = fmaf(c1, c2, mo[7]); mo[8] = fmaf(c2, c2, mo[8]);

#pragma unroll
        for (int g = 0; g < 4; ++g) {
            floatx2 G0 = {gcur[g][0], gcur[g][0]};
            floatx2 G1 = {gcur[g][1], gcur[g][1]};
            bf16x8 Af;
#pragma unroll
            for (int jp = 0; jp < 4; ++jp) {
                floatx2 h = __builtin_elementwise_fma(
                    G0, w1a2[jp], __builtin_elementwise_fma(G1, w1b2[jp], b1r2[jp]));
                h = __builtin_elementwise_max(h, zero2);
                Af[2 * jp]     = (__bf16)h[0];
                Af[2 * jp + 1] = (__bf16)h[1];
            }
#pragma unroll
            for (int t = 0; t < 4; ++t) {
                // D != C: biasC stays live, no per-MFMA C-init movs
                floatx4 D = __builtin_amdgcn_mfma_f32_16x16x32_bf16(Af, Bf[t], biasC[t], 0, 0, 0);
                vmaxr[t] = fmaxf(fmaxf(D[0], D[1]),
                                 fmaxf(fmaxf(D[2], D[3]), vmaxr[t]));
                floatx2 d01 = {D[0], D[1]}, d23 = {D[2], D[3]};
                floatx2 p01 = __builtin_elementwise_max(d01, zero2);
                floatx2 p23 = __builtin_elementwise_max(d23, zero2);
                vsum[t] += p01 + p23;                                // v_pk_add_f32
                vsq[t]   = __builtin_elementwise_fma(p01, p01,       // v_pk_fma_f32
                               __builtin_elementwise_fma(p23, p23, vsq[t]));
            }
        }

        // pipeline sem for it+1: write then read-back NOW, consume next iter.
        // In-order DS pipe + same-wave write->read (R14 idiom, no barrier);
        // the round-trip latency overlaps rotate+branch+prefetch+moments.
        const int nb = (it + 1) & 1;
        sem_lds[nb][wave][lane] = (floatx2){n3, n4};
#pragma unroll
        for (int g = 0; g < 4; ++g)
            gcur[g] = sem_lds[nb][wave][g * 16 + l15];

        // rotate pipeline registers
        c0 = n0; c1 = n1; c2 = n2;
        pc += 320;   // 64 points * 5 floats
    }

    // finalize packed accumulators, then combine quads (lanes sharing l15)
    float vmax[4], vs[4], vq[4];
#pragma unroll
    for (int t = 0; t < 4; ++t) {
        vmax[t] = vmaxr[t];                    // == max over relu'd (init 0)
        vs[t]   = vsum[t][0] + vsum[t][1];
        vq[t]   = vsq[t][0] + vsq[t][1];
        vmax[t] = fmaxf(vmax[t], __shfl_xor(vmax[t], 16));
        vmax[t] = fmaxf(vmax[t], __shfl_xor(vmax[t], 32));
        vs[t] += __shfl_xor(vs[t], 16);
        vs[t] += __shfl_xor(vs[t], 32);
        vq[t] += __shfl_xor(vq[t], 16);
        vq[t] += __shfl_xor(vq[t], 32);
    }
#pragma unroll
    for (int j = 0; j < 9; ++j) {
        float v = mo[j];
#pragma unroll
        for (int o = 32; o > 0; o >>= 1) v += __shfl_xor(v, o);
        mo[j] = v;
    }

    __shared__ float red[4][201];
    if (quad == 0) {
#pragma unroll
        for (int t = 0; t < 4; ++t) {
            red[wave][t * 16 + l15]       = vmax[t];
            red[wave][64 + t * 16 + l15]  = vs[t];
            red[wave][128 + t * 16 + l15] = vq[t];
        }
    }
    if (lane == 0) {
#pragma unroll
        for (int j = 0; j < 9; ++j) red[wave][192 + j] = mo[j];
    }
    __syncthreads();

    // non-atomic partial write: slot (b*P1_CHUNKS + chunk)
    if (tid < 201) {
        float v0 = red[0][tid], v1 = red[1][tid], v2 = red[2][tid], v3 = red[3][tid];
        float r = (tid < 64) ? fmaxf(fmaxf(v0, v1), fmaxf(v2, v3))
                             : (v0 + v1) + (v2 + v3);
        ws[(size_t)(b * P1_CHUNKS + chunk) * PART_STRIDE + tid] = r;
    }
}

// ---------------- fused mid: reduce partials + eigh + extents + final MLP ----------------
// R15 version (verified best, 204.2 total): all-thread eigh in registers
// (uniform branches, cndmask column selects — rule-#20 safe), no eg[] LDS
// round-trip, extents scan unroll 8, split-K MLP.
__global__ __launch_bounds__(MID_TPB)
void mid_kernel(const float* __restrict__ x,
                const float* __restrict__ W3, const float* __restrict__ b3,
                const float* __restrict__ W4, const float* __restrict__ b4,
                const float* __restrict__ W5, const float* __restrict__ b5,
                const float* __restrict__ ws, float* __restrict__ out) {
    const int b = blockIdx.x, t = threadIdx.x;
    const int lane = t & 63, wave = t >> 6;

    __shared__ float comb[201];
    __shared__ float redmm[16][8];
    __shared__ float g[224];
    __shared__ float h1[256];
    __shared__ float h2[128];
    __shared__ float part[8][256];  // split-K partial sums

    // --- reduce the 8 per-chunk partials ---
    if (t < 201) {
        const float* base = ws + (size_t)b * P1_CHUNKS * PART_STRIDE + t;
        float acc = base[0];
        if (t < 64) {
#pragma unroll
            for (int i = 1; i < P1_CHUNKS; ++i) acc = fmaxf(acc, base[i * PART_STRIDE]);
        } else {
#pragma unroll
            for (int i = 1; i < P1_CHUNKS; ++i) acc += base[i * PART_STRIDE];
        }
        comb[t] = acc;
    }
    __syncthreads();

    // --- all-thread fp32 Jacobi eigh (uniform data => uniform branches) ---
    const float nin = 1.0f / (float)NPTS;
    const float cx = comb[192] * nin, cy = comb[193] * nin, cz = comb[194] * nin;
    float A[3][3];
    A[0][0] = comb[195] * nin - cx * cx; A[0][1] = comb[196] * nin - cx * cy;
    A[0][2] = comb[197] * nin - cx * cz;
    A[1][1] = comb[198] * nin - cy * cy; A[1][2] = comb[199] * nin - cy * cz;
    A[2][2] = comb[200] * nin - cz * cz;
    A[1][0] = A[0][1]; A[2][0] = A[0][2]; A[2][1] = A[1][2];
    float V[3][3] = {{1, 0, 0}, {0, 1, 0}, {0, 0, 1}};
    {
        const int PP[3] = {0, 0, 1};
        const int QQ[3] = {1, 2, 2};
        for (int sweep = 0; sweep < 7; ++sweep) {
#pragma unroll
            for (int r3 = 0; r3 < 3; ++r3) {
                int p = PP[r3], q = QQ[r3];
                float apq = A[p][q];
                if (fabsf(apq) < 1e-35f) continue;
                float theta = (A[q][q] - A[p][p]) / (2.0f * apq);
                float tt = 1.0f / (fabsf(theta) + sqrtf(fmaf(theta, theta, 1.0f)));
                if (theta < 0.0f) tt = -tt;
                float c = 1.0f / sqrtf(fmaf(tt, tt, 1.0f)), s = tt * c;
                float apq_t = tt * apq;
                A[p][p] -= apq_t;
                A[q][q] += apq_t;
                A[p][q] = A[q][p] = 0.0f;
#pragma unroll
                for (int r = 0; r < 3; ++r) {
                    if (r != p && r != q) {
                        float arp = A[r][p], arq = A[r][q];
                        A[r][p] = A[p][r] = c * arp - s * arq;
                        A[r][q] = A[q][r] = s * arp + c * arq;
                    }
                    float vrp = V[r][p], vrq = V[r][q];
                    V[r][p] = c * vrp - s * vrq;
                    V[r][q] = s * vrp + c * vrq;
                }
            }
        }
    }
    float w0 = A[0][0], w1v = A[1][1], w2v = A[2][2];
    int i0 = 0, i1 = 1, i2 = 2, sw;
    {
        float wa = w0, wb = w1v, wc = w2v, swf;
        if (wa < wb) { sw = i0; i0 = i1; i1 = sw; swf = wa; wa = wb; wb = swf; }
        if (wa < wc) { sw = i0; i0 = i2; i2 = sw; swf = wa; wa = wc; wc = swf; }
        if (wb < wc) { sw = i1; i1 = i2; i2 = sw; swf = wb; wb = wc; wc = swf; }
    }
#define SEL3(a0, a1, a2, id) ((id) == 0 ? (a0) : ((id) == 1 ? (a1) : (a2)))
    const float e0x = SEL3(V[0][0], V[0][1], V[0][2], i0);
    const float e0y = SEL3(V[1][0], V[1][1], V[1][2], i0);
    const float e0z = SEL3(V[2][0], V[2][1], V[2][2], i0);
    const float e1x = SEL3(V[0][0], V[0][1], V[0][2], i1);
    const float e1y = SEL3(V[1][0], V[1][1], V[1][2], i1);
    const float e1z = SEL3(V[2][0], V[2][1], V[2][2], i1);
    const float e2x = SEL3(V[0][0], V[0][1], V[0][2], i2);
    const float e2y = SEL3(V[1][0], V[1][1], V[1][2], i2);
    const float e2z = SEL3(V[2][0], V[2][1], V[2][2], i2);
    const float esum = w0 + w1v + w2v + 1e-8f;
    const float ena = SEL3(w0, w1v, w2v, i0) / esum;
    const float enb = SEL3(w0, w1v, w2v, i1) / esum;
    const float enc = SEL3(w0, w1v, w2v, i2) / esum;
#undef SEL3

    // --- projection extents over this batch's 16384 points (16 waves) ---
    const float* xb = x + (size_t)b * NPTS * 5;
    float mn[3] = {3.4e38f, 3.4e38f, 3.4e38f};
    float mx3[3] = {-3.4e38f, -3.4e38f, -3.4e38f};
#pragma unroll 8
    for (int i = 0; i < NPTS / MID_TPB; ++i) {
        const float* p = xb + (size_t)(i * MID_TPB + t) * 5;
        float c0 = p[0] - cx, c1 = p[1] - cy, c2 = p[2] - cz;
        float p0 = fmaf(c0, e0x, fmaf(c1, e0y, c2 * e0z));
        float p1 = fmaf(c0, e1x, fmaf(c1, e1y, c2 * e1z));
        float p2 = fmaf(c0, e2x, fmaf(c1, e2y, c2 * e2z));
        mn[0] = fminf(mn[0], p0); mx3[0] = fmaxf(mx3[0], p0);
        mn[1] = fminf(mn[1], p1); mx3[1] = fmaxf(mx3[1], p1);
        mn[2] = fminf(mn[2], p2); mx3[2] = fmaxf(mx3[2], p2);
    }
#pragma unroll
    for (int d = 0; d < 3; ++d) {
        float v = mx3[d];
#pragma unroll
        for (int o = 32; o > 0; o >>= 1) v = fmaxf(v, __shfl_xor(v, o));
        if (lane == 0) redmm[wave][d] = v;
        float u = mn[d];
#pragma unroll
        for (int o = 32; o > 0; o >>= 1) u = fminf(u, __shfl_xor(u, o));
        if (lane == 0) redmm[wave][4 + d] = u;
    }
    __syncthreads();

    // --- assemble g(201) ---
    if (t < 64) {
        g[t] = comb[t];
        float s = comb[64 + t], sq = comb[128 + t];
        float avg = s * (1.0f / NPTS);
        g[64 + t] = avg;
        float var = (sq - s * avg) / (float)(NPTS - 1);
        g[128 + t] = sqrtf(fmaxf(var, 0.f));
    } else if (t < 73) {
        int j = t - 64;
        if (j < 3) {
            g[192 + j] = (j == 0) ? ena : ((j == 1) ? enb : enc);
        } else if (j < 6) {
            int d = j - 3;
            float fmx = redmm[0][d], fmn = redmm[0][4 + d];
#pragma unroll
            for (int w2 = 1; w2 < 16; ++w2) {
                fmx = fmaxf(fmx, redmm[w2][d]);
                fmn = fminf(fmn, redmm[w2][4 + d]);
            }
            g[195 + d] = fmx - fmn;
        } else {
            int d = j - 6;
            g[198 + d] = (d == 0) ? cx : ((d == 1) ? cy : cz);
        }
    }
    __syncthreads();

    // --- final MLP 201 -> 256 -> 128 -> 256, split-K over waves ---
    {
        int p = t >> 8, c = t & 255;
        int j0 = p * 51, j1 = min(201, j0 + 51);
        float a = 0.f;
        for (int j = j0; j < j1; ++j) a = fmaf(g[j], W3[j * 256 + c], a);
        part[p][c] = a;
    }
    __syncthreads();
    if (t < 256) {
        float a = b3[t] + (part[0][t] + part[1][t]) + (part[2][t] + part[3][t]);
        h1[t] = fmaxf(a, 0.f);
    }
    __syncthreads();
    {
        int p = t >> 7, c = t & 127;
        int j0 = p * 32;
        float a = 0.f;
#pragma unroll
        for (int j = j0; j < j0 + 32; ++j) a = fmaf(h1[j], W4[j * 128 + c], a);
        part[p][c] = a;
    }
    __syncthreads();
    if (t < 128) {
        float a = b4[t];
#pragma unroll
        for (int p = 0; p < 8; ++p) a += part[p][t];
        h2[t] = fmaxf(a, 0.f);
    }
    __syncthreads();
    {
        int p = t >> 8, c = t & 255;
        int j0 = p * 32;
        float a = 0.f;
#pragma unroll
        for (int j = j0; j < j0 + 32; ++j) a = fmaf(h2[j], W5[j * 256 + c], a);
        part[p][c] = a;
    }
    __syncthreads();
    if (t < 256) {
        float o = b5[t] + (part[0][t] + part[1][t]) + (part[2][t] + part[3][t]);
        out[(size_t)b * 256 + t] = o;
    }
}

extern "C" void kernel_launch(void* const* d_in, const int* in_sizes, int n_in,
                              void* d_out, int out_size, void* d_ws, size_t ws_size,
                              hipStream_t stream) {
    const float* x  = (const float*)d_in[0];
    const float* W1 = (const float*)d_in[1];
    const float* b1 = (const float*)d_in[2];
    const float* W2 = (const float*)d_in[3];
    const float* b2 = (const float*)d_in[4];
    const float* W3 = (const float*)d_in[5];
    const float* b3 = (const float*)d_in[6];
    const float* W4 = (const float*)d_in[7];
    const float* b4 = (const float*)d_in[8];
    const float* W5 = (const float*)d_in[9];
    const float* b5 = (const float*)d_in[10];
    float* out = (float*)d_out;
    float* ws  = (float*)d_ws;

    pass1_kernel<<<dim3(BATCH, P1_CHUNKS), TPB, 0, stream>>>(x, W1, b1, W2, b2, ws);
    mid_kernel<<<dim3(BATCH), MID_TPB, 0, stream>>>(x, W3, b3, W4, b4, W5, b5, ws, out);
}